// Round 1
// baseline (354.599 us; speedup 1.0000x reference)
//
#include <hip/hip_runtime.h>

// BatchReLUTransformer: element-wise ReLU-relaxation bound propagation.
// Inputs (fp32): bounds (N,B,2), beta (N,B), last_bounds (N,B,2)
// Output (fp32): (N,B,2) = stack([out_l, out_u], axis=2)
// Memory-bound streaming, 470 MB logical traffic/dispatch.
// R1 state: 84 us/dispatch, FETCH=163.9MB (L3 serves 50% of reads), logical
// BW 5.6 TB/s. This round:
//  - drop nontemporal hint on LOADS (evict-first was fighting the L3's
//    inter-iteration retention of inputs; FETCH_SIZE proves reuse exists);
//    KEEP nontemporal on stores (output is pure L3 pollution).
//  - block-granular bounds check: full blocks (the only kind at this shape)
//    take a branch-free path -> loads issue as one unbroken 12-load burst.

typedef float v4f __attribute__((ext_vector_type(4)));
typedef float v2f __attribute__((ext_vector_type(2)));

__device__ __forceinline__ v2f relax_pair(float l, float u, float beta,
                                          float ll, float lu) {
    const bool ind1 = (u <= 0.0f);               // always inactive
    const bool ind2 = (l > 0.0f);                // always active
    const bool ind3 = (u > 0.0f) && (l < 0.0f);  // unstable

    const float diff  = ind3 ? (u - l) : 1.0f;   // safe divisor
    const float inv   = 1.0f / diff;
    const float lmbda = ind2 ? 1.0f : (ind3 ? u * inv : 0.0f);
    const float mu    = ind3 ? (-l * u * inv) : 0.0f;
    const float beff  = ind1 ? 0.0f : (ind2 ? 1.0f : beta);

    const float cur_l = ind2 ? l : 0.0f;
    const float cur_u = ind2 ? u : (ind3 ? u : 0.0f);

    const float new_l = fmaxf(beff, 0.0f) * ll + fminf(beff, 0.0f) * lu;
    const float new_u = fmaxf(lmbda, 0.0f) * lu + fminf(lmbda, 0.0f) * ll + mu;

    v2f r;
    r.x = fmaxf(cur_l, new_l);
    r.y = fminf(cur_u, new_u);
    return r;
}

constexpr int UNROLL = 4;
constexpr int BLOCK  = 256;

// Each block covers a contiguous chunk of UNROLL*BLOCK float4-items; thread t
// handles items t + k*BLOCK (k=0..3) -> every access wave-coalesced, 12
// independent loads in flight per thread before first use.
// Blocks with blockIdx.x < full_blocks are provably in-bounds: no per-item
// predication, loads issue back-to-back. Only a (possible) final partial
// block pays the checks.
__global__ __launch_bounds__(BLOCK) void batch_relu_transformer_kernel(
    const v4f* __restrict__ bounds,      // 2 (l,u) pairs per item
    const v2f* __restrict__ beta,
    const v4f* __restrict__ last_bounds,
    v4f* __restrict__ out,
    long long n4, long long full_blocks) {
    const long long base =
        (long long)blockIdx.x * (BLOCK * UNROLL) + threadIdx.x;

    if ((long long)blockIdx.x < full_blocks) {
        // ---- fast path: whole chunk in range, branch-free ----
        v4f b[UNROLL], lb[UNROLL];
        v2f be[UNROLL];
#pragma unroll
        for (int k = 0; k < UNROLL; ++k) {
            const long long idx = base + (long long)k * BLOCK;
            b[k]  = bounds[idx];        // cached: let L3 retain across iters
            lb[k] = last_bounds[idx];
            be[k] = beta[idx];
        }
#pragma unroll
        for (int k = 0; k < UNROLL; ++k) {
            const long long idx = base + (long long)k * BLOCK;
            const v2f p0 = relax_pair(b[k].x, b[k].y, be[k].x, lb[k].x, lb[k].y);
            const v2f p1 = relax_pair(b[k].z, b[k].w, be[k].y, lb[k].z, lb[k].w);
            v4f o;
            o.x = p0.x; o.y = p0.y; o.z = p1.x; o.w = p1.y;
            __builtin_nontemporal_store(o, &out[idx]);  // keep out of L3
        }
    } else {
        // ---- tail block: per-item checks (at most one such block) ----
#pragma unroll
        for (int k = 0; k < UNROLL; ++k) {
            const long long idx = base + (long long)k * BLOCK;
            if (idx < n4) {
                const v4f b  = bounds[idx];
                const v4f lb = last_bounds[idx];
                const v2f be = beta[idx];
                const v2f p0 = relax_pair(b.x, b.y, be.x, lb.x, lb.y);
                const v2f p1 = relax_pair(b.z, b.w, be.y, lb.z, lb.w);
                v4f o;
                o.x = p0.x; o.y = p0.y; o.z = p1.x; o.w = p1.y;
                __builtin_nontemporal_store(o, &out[idx]);
            }
        }
    }
}

// Scalar tail for an odd final pair (n_pairs odd; not expected here, but safe).
__global__ void batch_relu_tail_kernel(const float* __restrict__ bounds,
                                       const float* __restrict__ beta,
                                       const float* __restrict__ last_bounds,
                                       float* __restrict__ out,
                                       long long pair_idx) {
    const float l  = bounds[2 * pair_idx];
    const float u  = bounds[2 * pair_idx + 1];
    const float ll = last_bounds[2 * pair_idx];
    const float lu = last_bounds[2 * pair_idx + 1];
    const v2f p = relax_pair(l, u, beta[pair_idx], ll, lu);
    out[2 * pair_idx]     = p.x;
    out[2 * pair_idx + 1] = p.y;
}

extern "C" void kernel_launch(void* const* d_in, const int* in_sizes, int n_in,
                              void* d_out, int out_size, void* d_ws, size_t ws_size,
                              hipStream_t stream) {
    const float* bounds      = (const float*)d_in[0];
    const float* beta        = (const float*)d_in[1];
    const float* last_bounds = (const float*)d_in[2];
    float* out = (float*)d_out;

    const long long n_pairs = (long long)in_sizes[1];  // beta count = N*B
    const long long n4 = n_pairs / 2;                  // float4 work items

    const long long per_block   = (long long)BLOCK * UNROLL;
    const long long grid        = (n4 + per_block - 1) / per_block;
    const long long full_blocks = n4 / per_block;      // provably in-bounds
    batch_relu_transformer_kernel<<<(dim3)(unsigned)grid, BLOCK, 0, stream>>>(
        (const v4f*)bounds, (const v2f*)beta, (const v4f*)last_bounds,
        (v4f*)out, n4, full_blocks);

    if (n_pairs & 1) {
        batch_relu_tail_kernel<<<1, 1, 0, stream>>>(bounds, beta, last_bounds,
                                                    out, n_pairs - 1);
    }
}

// Round 3
// 326.107 us; speedup vs baseline: 1.0874x; 1.0874x over previous
//
#include <hip/hip_runtime.h>

// BatchReLUTransformer: element-wise ReLU-relaxation bound propagation.
// Inputs (fp32): bounds (N,B,2), beta (N,B), last_bounds (N,B,2)
// Output (fp32): (N,B,2) = stack([out_l, out_u], axis=2)
// Memory-bound streaming, 470 MB logical traffic/dispatch.
//
// R1 lesson (within-session A/B): __builtin_nontemporal_load on the input
// streams is worth 1.7x (84 -> 143 us when removed; FETCH_SIZE unchanged).
// Interpretation: nt governs L2 allocation, not MALL. 470 MB working set
// thrashes the 32 MB aggregate L2 -> write-allocate traffic on the XCD
// fabric port for zero hit benefit; nt streams past L2. The MALL retains
// ~50% of reads across iterations regardless of the hint.
// => nt on ALL loads and stores. Keep block-granular fast path (VALU ↓).
// R2 lever: UNROLL 4 -> 8 (24 loads in flight/thread) to ride out fabric
// stall bursts; we are at 89% of copy ceiling with HBM only 44% busy.
// (R2 bench was an infra failure — this is the same kernel resubmitted.)

typedef float v4f __attribute__((ext_vector_type(4)));
typedef float v2f __attribute__((ext_vector_type(2)));

__device__ __forceinline__ v2f relax_pair(float l, float u, float beta,
                                          float ll, float lu) {
    const bool ind1 = (u <= 0.0f);               // always inactive
    const bool ind2 = (l > 0.0f);                // always active
    const bool ind3 = (u > 0.0f) && (l < 0.0f);  // unstable

    const float diff  = ind3 ? (u - l) : 1.0f;   // safe divisor
    const float inv   = 1.0f / diff;
    const float lmbda = ind2 ? 1.0f : (ind3 ? u * inv : 0.0f);
    const float mu    = ind3 ? (-l * u * inv) : 0.0f;
    const float beff  = ind1 ? 0.0f : (ind2 ? 1.0f : beta);

    const float cur_l = ind2 ? l : 0.0f;
    const float cur_u = ind2 ? u : (ind3 ? u : 0.0f);

    const float new_l = fmaxf(beff, 0.0f) * ll + fminf(beff, 0.0f) * lu;
    const float new_u = fmaxf(lmbda, 0.0f) * lu + fminf(lmbda, 0.0f) * ll + mu;

    v2f r;
    r.x = fmaxf(cur_l, new_l);
    r.y = fminf(cur_u, new_u);
    return r;
}

constexpr int UNROLL = 8;
constexpr int BLOCK  = 256;

// Each block covers a contiguous chunk of UNROLL*BLOCK float4-items; thread t
// handles items t + k*BLOCK -> every access wave-coalesced (64 lanes x 16B
// contiguous per instruction); 24 independent loads in flight per thread
// before first use.
// Blocks with blockIdx.x < full_blocks are provably in-bounds: no per-item
// predication, loads issue as one unbroken burst. Only a (possible) final
// partial block pays per-item checks.
__global__ __launch_bounds__(BLOCK) void batch_relu_transformer_kernel(
    const v4f* __restrict__ bounds,      // 2 (l,u) pairs per item
    const v2f* __restrict__ beta,
    const v4f* __restrict__ last_bounds,
    v4f* __restrict__ out,
    long long n4, long long full_blocks) {
    const long long base =
        (long long)blockIdx.x * (BLOCK * UNROLL) + threadIdx.x;

    if ((long long)blockIdx.x < full_blocks) {
        // ---- fast path: whole chunk in range, branch-free ----
        v4f b[UNROLL], lb[UNROLL];
        v2f be[UNROLL];
#pragma unroll
        for (int k = 0; k < UNROLL; ++k) {
            const long long idx = base + (long long)k * BLOCK;
            b[k]  = __builtin_nontemporal_load(&bounds[idx]);
            lb[k] = __builtin_nontemporal_load(&last_bounds[idx]);
            be[k] = __builtin_nontemporal_load(&beta[idx]);
        }
#pragma unroll
        for (int k = 0; k < UNROLL; ++k) {
            const long long idx = base + (long long)k * BLOCK;
            const v2f p0 = relax_pair(b[k].x, b[k].y, be[k].x, lb[k].x, lb[k].y);
            const v2f p1 = relax_pair(b[k].z, b[k].w, be[k].y, lb[k].z, lb[k].w);
            v4f o;
            o.x = p0.x; o.y = p0.y; o.z = p1.x; o.w = p1.y;
            __builtin_nontemporal_store(o, &out[idx]);
        }
    } else {
        // ---- tail block: per-item checks (at most one such block) ----
#pragma unroll
        for (int k = 0; k < UNROLL; ++k) {
            const long long idx = base + (long long)k * BLOCK;
            if (idx < n4) {
                const v4f b  = __builtin_nontemporal_load(&bounds[idx]);
                const v4f lb = __builtin_nontemporal_load(&last_bounds[idx]);
                const v2f be = __builtin_nontemporal_load(&beta[idx]);
                const v2f p0 = relax_pair(b.x, b.y, be.x, lb.x, lb.y);
                const v2f p1 = relax_pair(b.z, b.w, be.y, lb.z, lb.w);
                v4f o;
                o.x = p0.x; o.y = p0.y; o.z = p1.x; o.w = p1.y;
                __builtin_nontemporal_store(o, &out[idx]);
            }
        }
    }
}

// Scalar tail for an odd final pair (n_pairs odd; not expected here, but safe).
__global__ void batch_relu_tail_kernel(const float* __restrict__ bounds,
                                       const float* __restrict__ beta,
                                       const float* __restrict__ last_bounds,
                                       float* __restrict__ out,
                                       long long pair_idx) {
    const float l  = bounds[2 * pair_idx];
    const float u  = bounds[2 * pair_idx + 1];
    const float ll = last_bounds[2 * pair_idx];
    const float lu = last_bounds[2 * pair_idx + 1];
    const v2f p = relax_pair(l, u, beta[pair_idx], ll, lu);
    out[2 * pair_idx]     = p.x;
    out[2 * pair_idx + 1] = p.y;
}

extern "C" void kernel_launch(void* const* d_in, const int* in_sizes, int n_in,
                              void* d_out, int out_size, void* d_ws, size_t ws_size,
                              hipStream_t stream) {
    const float* bounds      = (const float*)d_in[0];
    const float* beta        = (const float*)d_in[1];
    const float* last_bounds = (const float*)d_in[2];
    float* out = (float*)d_out;

    const long long n_pairs = (long long)in_sizes[1];  // beta count = N*B
    const long long n4 = n_pairs / 2;                  // float4 work items

    const long long per_block   = (long long)BLOCK * UNROLL;
    const long long grid        = (n4 + per_block - 1) / per_block;
    const long long full_blocks = n4 / per_block;      // provably in-bounds
    batch_relu_transformer_kernel<<<(dim3)(unsigned)grid, BLOCK, 0, stream>>>(
        (const v4f*)bounds, (const v2f*)beta, (const v4f*)last_bounds,
        (v4f*)out, n4, full_blocks);

    if (n_pairs & 1) {
        batch_relu_tail_kernel<<<1, 1, 0, stream>>>(bounds, beta, last_bounds,
                                                    out, n_pairs - 1);
    }
}